// Round 2
// baseline (278.571 us; speedup 1.0000x reference)
//
#include <hip/hip_runtime.h>
#include <math.h>

// B=2, T=2048, D=768, H=12, HD=64
typedef __attribute__((ext_vector_type(8))) __bf16 bf16x8;
typedef __attribute__((ext_vector_type(4))) __bf16 bf16x4;
typedef __attribute__((ext_vector_type(4))) float f32x4;

#define GLOAD_LDS16(gsrc, ldst) \
  __builtin_amdgcn_global_load_lds((__attribute__((address_space(1))) const void*)(gsrc), \
                                   (__attribute__((address_space(3))) void*)(ldst), 16, 0, 0)

__global__ void cvt_bf16_kernel(const float* __restrict__ in, __bf16* __restrict__ out, int n4) {
  int i = blockIdx.x * 256 + threadIdx.x;
  if (i < n4) {
    float4 f = ((const float4*)in)[i];
    bf16x4 o;
    o[0] = (__bf16)f.x; o[1] = (__bf16)f.y; o[2] = (__bf16)f.z; o[3] = (__bf16)f.w;
    ((bf16x4*)out)[i] = o;
  }
}

// Tiled transpose-convert: out[C][R] = (bf16) in[R][C]. 32x32 tiles via LDS.
__global__ __launch_bounds__(256)
void cvtT_bf16_kernel(const float* __restrict__ in, __bf16* __restrict__ out, int R, int C) {
  __shared__ float t[32][33];
  int c0 = blockIdx.x * 32, r0 = blockIdx.y * 32;
  int tc = threadIdx.x & 31, tr = threadIdx.x >> 5;  // tr in [0,8)
#pragma unroll
  for (int i = 0; i < 4; ++i)
    t[tr + 8 * i][tc] = in[(size_t)(r0 + tr + 8 * i) * C + c0 + tc];
  __syncthreads();
#pragma unroll
  for (int i = 0; i < 4; ++i)
    out[(size_t)(c0 + tr + 8 * i) * R + r0 + tc] = (__bf16)t[tc][tr + 8 * i];
}

// TN GEMM: C[M][N] = A[M][K] * B[N][K]^T (+bias). 128x128 tile, BK=64, 4 waves.
// EPI 0: qkv epilogue (bias, q-scale, q/k -> [B,H,T,64], v -> V^T [B,H,64,T])
// EPI 1: out-proj epilogue (bias, fp32 row-major to d_out)
template<int EPI>
__global__ __launch_bounds__(256)
void gemm_tn_kernel(const __bf16* __restrict__ A, const __bf16* __restrict__ Bm,
                    const float* __restrict__ bias, float* __restrict__ outF,
                    __bf16* __restrict__ qo, __bf16* __restrict__ ko, __bf16* __restrict__ vo,
                    int M, int N, int K) {
  const int lane = threadIdx.x & 63;
  const int wave = threadIdx.x >> 6;
  const int r16 = lane & 15, g = lane >> 4;
  const int mBase = blockIdx.y * 128, nBase = blockIdx.x * 128;
  __shared__ __align__(16) __bf16 lds[16384];  // 16KB A (segs 0..15) + 16KB B (segs 16..31)

  f32x4 acc[4][4];
#pragma unroll
  for (int i = 0; i < 4; ++i)
#pragma unroll
    for (int j = 0; j < 4; ++j) acc[i][j] = (f32x4){0.f, 0.f, 0.f, 0.f};

  const int mw = (wave >> 1) * 4;
  const int nw = (wave & 1) * 4;

  for (int kt = 0; kt < K; kt += 64) {
#pragma unroll
    for (int i = 0; i < 8; ++i) {
      int seg = wave * 8 + i;                 // 0..31
      int isB = seg >> 4, ks = (seg >> 3) & 1, t8 = seg & 7;
      int row = (isB ? nBase : mBase) + t8 * 16 + r16;
      const __bf16* src = (isB ? Bm : A) + (size_t)row * K + kt + ks * 32 + g * 8;
      GLOAD_LDS16(src, &lds[seg * 512]);
    }
    __syncthreads();
#pragma unroll
    for (int ks = 0; ks < 2; ++ks) {
      bf16x8 af[4], bfr[4];
#pragma unroll
      for (int i = 0; i < 4; ++i) af[i] = *(const bf16x8*)&lds[((ks * 8 + mw + i) * 64 + lane) * 8];
#pragma unroll
      for (int j = 0; j < 4; ++j) bfr[j] = *(const bf16x8*)&lds[((16 + ks * 8 + nw + j) * 64 + lane) * 8];
#pragma unroll
      for (int i = 0; i < 4; ++i)
#pragma unroll
        for (int j = 0; j < 4; ++j)
          acc[i][j] = __builtin_amdgcn_mfma_f32_16x16x32_bf16(af[i], bfr[j], acc[i][j], 0, 0, 0);
    }
    __syncthreads();
  }

#pragma unroll
  for (int i = 0; i < 4; ++i) {
#pragma unroll
    for (int j = 0; j < 4; ++j) {
      int c = nBase + (nw + j) * 16 + r16;
      float bb = bias[c];
#pragma unroll
      for (int e = 0; e < 4; ++e) {
        int r = mBase + (mw + i) * 16 + g * 4 + e;
        float val = acc[i][j][e] + bb;
        if (EPI == 0) {
          int which = c / 768;             // 0:q 1:k 2:v
          int cc = c - which * 768;
          int hh = cc >> 6, dd = cc & 63;
          int bI = r >> 11, tt = r & 2047;
          if (which == 0) {
            qo[(((size_t)(bI * 12 + hh)) * 2048 + tt) * 64 + dd] = (__bf16)(val * 0.125f);
          } else if (which == 1) {
            ko[(((size_t)(bI * 12 + hh)) * 2048 + tt) * 64 + dd] = (__bf16)val;
          } else {
            // V^T: [B,H,64,T]
            vo[(((size_t)(bI * 12 + hh)) * 64 + dd) * 2048 + tt] = (__bf16)val;
          }
        } else {
          outF[(size_t)r * N + c] = val;
        }
      }
    }
  }
}

// Flash attention, causal, swapped-QK^T. Grid (qt=T/64, B*H). 4 waves x 16 q-rows.
// S^T = mfma(K_frag, Q_frag): lane holds 16 S values for the single q-row q=lane&15
// -> softmax reductions are 2 shfl_xor ops; m/l/alpha are per-lane scalars.
// V^T is read straight from global (L2-resident); no V staging, one barrier/iter.
__global__ __launch_bounds__(256)
void attn_kernel(const __bf16* __restrict__ qg, const __bf16* __restrict__ kg,
                 const __bf16* __restrict__ vtg, __bf16* __restrict__ yatt) {
  const int qt = blockIdx.x, bh = blockIdx.y;
  const int lane = threadIdx.x & 63, wave = threadIdx.x >> 6;
  const int r16 = lane & 15, g = lane >> 4;
  const int bI = bh / 12, h = bh - bI * 12;
  const size_t headoff = (size_t)bh * 2048 * 64;
  const __bf16* Q = qg + headoff;
  const __bf16* Kh = kg + headoff;
  const __bf16* VT = vtg + headoff;   // [64][2048]

  __shared__ __align__(16) __bf16 Plds[4][16][72];  // per-wave P strip [q][k]

  const int tq = qt * 64 + wave * 16 + r16;
  bf16x8 qf[2];
  qf[0] = *(const bf16x8*)&Q[(size_t)tq * 64 + g * 8];
  qf[1] = *(const bf16x8*)&Q[(size_t)tq * 64 + 32 + g * 8];

  f32x4 o[4];   // rows q = 4g+e (within wave tile), cols d = dj*16+r16
#pragma unroll
  for (int j = 0; j < 4; ++j) o[j] = (f32x4){0.f, 0.f, 0.f, 0.f};
  float m = -INFINITY, l = 0.f;   // for q-row = r16

  for (int kt = 0; kt <= qt; ++kt) {
    // S^T[k][q]: 4 k-tiles of 16; A = K rows (k, d-contig), B = Q
    f32x4 st[4];
#pragma unroll
    for (int j = 0; j < 4; ++j) st[j] = (f32x4){0.f, 0.f, 0.f, 0.f};
#pragma unroll
    for (int ks = 0; ks < 2; ++ks) {
#pragma unroll
      for (int j = 0; j < 4; ++j) {
        bf16x8 kf = *(const bf16x8*)&Kh[(size_t)(kt * 64 + j * 16 + r16) * 64 + ks * 32 + g * 8];
        st[j] = __builtin_amdgcn_mfma_f32_16x16x32_bf16(kf, qf[ks], st[j], 0, 0, 0);
      }
    }
    if (kt == qt) {  // causal: mask k > q.  k = j*16+4g+e, q = wave*16+r16 (tile-local)
#pragma unroll
      for (int j = 0; j < 4; ++j)
#pragma unroll
        for (int e = 0; e < 4; ++e)
          if (j * 16 + 4 * g + e > wave * 16 + r16) st[j][e] = -INFINITY;
    }
    // online softmax, per-lane row q=r16 (16 values local, 4 g-copies across lanes)
    float mt = -INFINITY;
#pragma unroll
    for (int j = 0; j < 4; ++j)
#pragma unroll
      for (int e = 0; e < 4; ++e) mt = fmaxf(mt, st[j][e]);
    mt = fmaxf(mt, __shfl_xor(mt, 16, 64));
    mt = fmaxf(mt, __shfl_xor(mt, 32, 64));
    float mn = fmaxf(m, mt);
    float alpha = __expf(m - mn);   // exp(-inf)=0 on first tile
    m = mn;
    float ls = 0.f;
#pragma unroll
    for (int j = 0; j < 4; ++j)
#pragma unroll
      for (int e = 0; e < 4; ++e) {
        float p = __expf(st[j][e] - mn);
        st[j][e] = p;
        ls += p;
      }
    ls += __shfl_xor(ls, 16, 64);
    ls += __shfl_xor(ls, 32, 64);
    l = l * alpha + ls;
    // rescale O: need alpha for q-row = 4g+e -> bpermute from lane (4g+e)
#pragma unroll
    for (int e = 0; e < 4; ++e) {
      float ae = __shfl(alpha, 4 * g + e, 64);
#pragma unroll
      for (int dj = 0; dj < 4; ++dj) o[dj][e] *= ae;
    }
    // P -> LDS [q=r16][k], packed 4-wide (k = 16j+4g+0..3)
#pragma unroll
    for (int j = 0; j < 4; ++j) {
      bf16x4 pk;
#pragma unroll
      for (int e = 0; e < 4; ++e) pk[e] = (__bf16)st[j][e];
      *(bf16x4*)&Plds[wave][r16][j * 16 + 4 * g] = pk;
    }
    __syncthreads();
    // PV: A = P[q][k] (rows q), B = V[k][d] via V^T global rows (d, k-contig)
#pragma unroll
    for (int ks = 0; ks < 2; ++ks) {
      bf16x8 pf = *(const bf16x8*)&Plds[wave][r16][ks * 32 + g * 8];
#pragma unroll
      for (int dj = 0; dj < 4; ++dj) {
        bf16x8 vf = *(const bf16x8*)&VT[(size_t)(dj * 16 + r16) * 2048 + kt * 64 + ks * 32 + g * 8];
        o[dj] = __builtin_amdgcn_mfma_f32_16x16x32_bf16(pf, vf, o[dj], 0, 0, 0);
      }
    }
  }
  // epilogue: l for q-row 4g+e lives at lane (4g+e)
  float le[4];
#pragma unroll
  for (int e = 0; e < 4; ++e) le[e] = __shfl(l, 4 * g + e, 64);
#pragma unroll
  for (int dj = 0; dj < 4; ++dj)
#pragma unroll
    for (int e = 0; e < 4; ++e) {
      float val = o[dj][e] / le[e];
      int t = qt * 64 + wave * 16 + 4 * g + e;
      yatt[((size_t)(bI * 2048 + t)) * 768 + h * 64 + dj * 16 + r16] = (__bf16)val;
    }
}

extern "C" void kernel_launch(void* const* d_in, const int* in_sizes, int n_in,
                              void* d_out, int out_size, void* d_ws, size_t ws_size,
                              hipStream_t stream) {
  (void)in_sizes; (void)n_in; (void)out_size; (void)ws_size;
  const float* x     = (const float*)d_in[0];
  const float* w_qkv = (const float*)d_in[1];
  const float* b_qkv = (const float*)d_in[2];
  const float* w_out = (const float*)d_in[3];
  const float* b_out = (const float*)d_in[4];
  float* out = (float*)d_out;

  char* ws = (char*)d_ws;
  __bf16* xb    = (__bf16*)(ws);              // [4096][768]
  __bf16* wqkvT = (__bf16*)(ws + 6291456);    // [2304][768]
  __bf16* woT   = (__bf16*)(ws + 9830400);    // [768][768]
  __bf16* qb    = (__bf16*)(ws + 11010048);   // [B,H,T,64]
  __bf16* kb    = (__bf16*)(ws + 17301504);   // [B,H,T,64]
  __bf16* vtb   = (__bf16*)(ws + 23592960);   // [B,H,64,T]  (V transposed)
  __bf16* yatt  = (__bf16*)(ws + 29884416);   // [4096][768]

  cvt_bf16_kernel<<<3072, 256, 0, stream>>>(x, xb, 786432);
  cvtT_bf16_kernel<<<dim3(72, 24), 256, 0, stream>>>(w_qkv, wqkvT, 768, 2304);
  cvtT_bf16_kernel<<<dim3(24, 24), 256, 0, stream>>>(w_out, woT, 768, 768);
  gemm_tn_kernel<0><<<dim3(18, 32), 256, 0, stream>>>(xb, wqkvT, b_qkv, nullptr,
                                                      qb, kb, vtb, 4096, 2304, 768);
  attn_kernel<<<dim3(32, 24), 256, 0, stream>>>(qb, kb, vtb, yatt);
  gemm_tn_kernel<1><<<dim3(6, 32), 256, 0, stream>>>(yatt, woT, b_out, out,
                                                     nullptr, nullptr, nullptr, 4096, 768, 768);
}

// Round 3
// 216.798 us; speedup vs baseline: 1.2849x; 1.2849x over previous
//
#include <hip/hip_runtime.h>
#include <math.h>

// B=2, T=2048, D=768, H=12, HD=64
typedef __attribute__((ext_vector_type(8))) __bf16 bf16x8;
typedef __attribute__((ext_vector_type(4))) __bf16 bf16x4;
typedef __attribute__((ext_vector_type(4))) float f32x4;

#define GLOAD_LDS16(gsrc, ldst) \
  __builtin_amdgcn_global_load_lds((__attribute__((address_space(1))) const void*)(gsrc), \
                                   (__attribute__((address_space(3))) void*)(ldst), 16, 0, 0)

__global__ void cvt_bf16_kernel(const float* __restrict__ in, __bf16* __restrict__ out, int n4) {
  int i = blockIdx.x * 256 + threadIdx.x;
  if (i < n4) {
    float4 f = ((const float4*)in)[i];
    bf16x4 o;
    o[0] = (__bf16)f.x; o[1] = (__bf16)f.y; o[2] = (__bf16)f.z; o[3] = (__bf16)f.w;
    ((bf16x4*)out)[i] = o;
  }
}

// Tiled transpose-convert: out[C][R] = (bf16) in[R][C]. 32x32 tiles via LDS.
__global__ __launch_bounds__(256)
void cvtT_bf16_kernel(const float* __restrict__ in, __bf16* __restrict__ out, int R, int C) {
  __shared__ float t[32][33];
  int c0 = blockIdx.x * 32, r0 = blockIdx.y * 32;
  int tc = threadIdx.x & 31, tr = threadIdx.x >> 5;
#pragma unroll
  for (int i = 0; i < 4; ++i)
    t[tr + 8 * i][tc] = in[(size_t)(r0 + tr + 8 * i) * C + c0 + tc];
  __syncthreads();
#pragma unroll
  for (int i = 0; i < 4; ++i)
    out[(size_t)(c0 + tr + 8 * i) * R + r0 + tc] = (__bf16)t[tc][tr + 8 * i];
}

// TN GEMM: C[M][N] = A[M][K] * B[N][K]^T (+bias). 128x128 tile, BK=64, 4 waves.
template<int EPI>
__global__ __launch_bounds__(256)
void gemm_tn_kernel(const __bf16* __restrict__ A, const __bf16* __restrict__ Bm,
                    const float* __restrict__ bias, float* __restrict__ outF,
                    __bf16* __restrict__ qo, __bf16* __restrict__ ko, __bf16* __restrict__ vo,
                    int M, int N, int K) {
  const int lane = threadIdx.x & 63;
  const int wave = threadIdx.x >> 6;
  const int r16 = lane & 15, g = lane >> 4;
  const int mBase = blockIdx.y * 128, nBase = blockIdx.x * 128;
  __shared__ __align__(16) __bf16 lds[16384];

  f32x4 acc[4][4];
#pragma unroll
  for (int i = 0; i < 4; ++i)
#pragma unroll
    for (int j = 0; j < 4; ++j) acc[i][j] = (f32x4){0.f, 0.f, 0.f, 0.f};

  const int mw = (wave >> 1) * 4;
  const int nw = (wave & 1) * 4;

  for (int kt = 0; kt < K; kt += 64) {
#pragma unroll
    for (int i = 0; i < 8; ++i) {
      int seg = wave * 8 + i;
      int isB = seg >> 4, ks = (seg >> 3) & 1, t8 = seg & 7;
      int row = (isB ? nBase : mBase) + t8 * 16 + r16;
      const __bf16* src = (isB ? Bm : A) + (size_t)row * K + kt + ks * 32 + g * 8;
      GLOAD_LDS16(src, &lds[seg * 512]);
    }
    __syncthreads();
#pragma unroll
    for (int ks = 0; ks < 2; ++ks) {
      bf16x8 af[4], bfr[4];
#pragma unroll
      for (int i = 0; i < 4; ++i) af[i] = *(const bf16x8*)&lds[((ks * 8 + mw + i) * 64 + lane) * 8];
#pragma unroll
      for (int j = 0; j < 4; ++j) bfr[j] = *(const bf16x8*)&lds[((16 + ks * 8 + nw + j) * 64 + lane) * 8];
#pragma unroll
      for (int i = 0; i < 4; ++i)
#pragma unroll
        for (int j = 0; j < 4; ++j)
          acc[i][j] = __builtin_amdgcn_mfma_f32_16x16x32_bf16(af[i], bfr[j], acc[i][j], 0, 0, 0);
    }
    __syncthreads();
  }

#pragma unroll
  for (int i = 0; i < 4; ++i) {
#pragma unroll
    for (int j = 0; j < 4; ++j) {
      int c = nBase + (nw + j) * 16 + r16;
      float bb = bias[c];
#pragma unroll
      for (int e = 0; e < 4; ++e) {
        int r = mBase + (mw + i) * 16 + g * 4 + e;
        float val = acc[i][j][e] + bb;
        if (EPI == 0) {
          int which = c / 768;             // 0:q 1:k 2:v
          int cc = c - which * 768;
          int hh = cc >> 6, dd = cc & 63;
          int bI = r >> 11, tt = r & 2047;
          if (which == 0) {
            qo[(((size_t)(bI * 12 + hh)) * 2048 + tt) * 64 + dd] = (__bf16)(val * 0.125f);
          } else if (which == 1) {
            ko[(((size_t)(bI * 12 + hh)) * 2048 + tt) * 64 + dd] = (__bf16)val;
          } else {
            vo[(((size_t)(bI * 12 + hh)) * 64 + dd) * 2048 + tt] = (__bf16)val;  // V^T [B,H,64,T]
          }
        } else {
          outF[(size_t)r * N + c] = val;
        }
      }
    }
  }
}

// Flash attention, causal, swapped-QK^T, barrier-free.
// Grid: 768 1-D blocks. id&7 = XCD chunk (3 heads -> K/V L2-resident per XCD);
// within chunk, heaviest q-tiles (qt=31) dispatch first (longest-first packing).
// Per iter: K loads issue first, V loads second (vmcnt FIFO: QK^T waits only for K,
// V stays in flight under softmax); next K tile prefetched during softmax/PV.
__global__ __launch_bounds__(256)
void attn_kernel(const __bf16* __restrict__ qg, const __bf16* __restrict__ kg,
                 const __bf16* __restrict__ vtg, __bf16* __restrict__ yatt) {
  const int id = blockIdx.x;
  const int chunk = id & 7, within = id >> 3;
  const int bh = chunk * 3 + (within >> 5);
  const int qt = 31 - (within & 31);
  const int lane = threadIdx.x & 63, wave = threadIdx.x >> 6;
  const int r16 = lane & 15, g = lane >> 4;
  const int bI = bh / 12, h = bh - bI * 12;
  const size_t headoff = (size_t)bh * 2048 * 64;
  const __bf16* Q = qg + headoff;
  const __bf16* Kh = kg + headoff;
  const __bf16* VT = vtg + headoff;   // [64][2048]

  __shared__ __align__(16) __bf16 Plds[4][16][72];  // per-wave strip; no cross-wave use

  const int tq = qt * 64 + wave * 16 + r16;
  bf16x8 qf[2];
  qf[0] = *(const bf16x8*)&Q[(size_t)tq * 64 + g * 8];
  qf[1] = *(const bf16x8*)&Q[(size_t)tq * 64 + 32 + g * 8];

  f32x4 o[4];
#pragma unroll
  for (int j = 0; j < 4; ++j) o[j] = (f32x4){0.f, 0.f, 0.f, 0.f};
  float m = -INFINITY, l = 0.f;

  auto loadK = [&](int kt, bf16x8 (&kf)[2][4]) {
#pragma unroll
    for (int ks = 0; ks < 2; ++ks)
#pragma unroll
      for (int j = 0; j < 4; ++j)
        kf[ks][j] = *(const bf16x8*)&Kh[(size_t)(kt * 64 + j * 16 + r16) * 64 + ks * 32 + g * 8];
  };

  auto body = [&](int kt, bf16x8 (&kc)[2][4], bf16x8 (&kn)[2][4]) {
    // V loads issue after K (kn prefetch below is after MFMA issue): in flight during softmax
    bf16x8 vf[2][4];
#pragma unroll
    for (int ks = 0; ks < 2; ++ks)
#pragma unroll
      for (int dj = 0; dj < 4; ++dj)
        vf[ks][dj] = *(const bf16x8*)&VT[(size_t)(dj * 16 + r16) * 2048 + kt * 64 + ks * 32 + g * 8];
    f32x4 st[4];
#pragma unroll
    for (int j = 0; j < 4; ++j) st[j] = (f32x4){0.f, 0.f, 0.f, 0.f};
#pragma unroll
    for (int ks = 0; ks < 2; ++ks)
#pragma unroll
      for (int j = 0; j < 4; ++j)
        st[j] = __builtin_amdgcn_mfma_f32_16x16x32_bf16(kc[ks][j], qf[ks], st[j], 0, 0, 0);
    if (kt < qt) loadK(kt + 1, kn);   // prefetch next K under softmax+PV
    if (kt == qt) {  // causal: k = j*16+4g+e, q = wave*16+r16 (tile-local)
#pragma unroll
      for (int j = 0; j < 4; ++j)
#pragma unroll
        for (int e = 0; e < 4; ++e)
          if (j * 16 + 4 * g + e > wave * 16 + r16) st[j][e] = -INFINITY;
    }
    // online softmax: lane owns q-row r16 (16 vals local; 4 lane-copies over g)
    float mt = -INFINITY;
#pragma unroll
    for (int j = 0; j < 4; ++j)
#pragma unroll
      for (int e = 0; e < 4; ++e) mt = fmaxf(mt, st[j][e]);
    mt = fmaxf(mt, __shfl_xor(mt, 16, 64));
    mt = fmaxf(mt, __shfl_xor(mt, 32, 64));
    float mn = fmaxf(m, mt);
    float alpha = __expf(m - mn);
    m = mn;
    float ls = 0.f;
#pragma unroll
    for (int j = 0; j < 4; ++j)
#pragma unroll
      for (int e = 0; e < 4; ++e) {
        float p = __expf(st[j][e] - mn);
        st[j][e] = p;
        ls += p;
      }
    ls += __shfl_xor(ls, 16, 64);
    ls += __shfl_xor(ls, 32, 64);
    l = l * alpha + ls;
#pragma unroll
    for (int e = 0; e < 4; ++e) {
      float ae = __shfl(alpha, 4 * g + e, 64);
#pragma unroll
      for (int dj = 0; dj < 4; ++dj) o[dj][e] *= ae;
    }
    // P -> per-wave LDS strip (same-wave RAW, ordered by lgkmcnt; NO barrier)
#pragma unroll
    for (int j = 0; j < 4; ++j) {
      bf16x4 pk;
#pragma unroll
      for (int e = 0; e < 4; ++e) pk[e] = (__bf16)st[j][e];
      *(bf16x4*)&Plds[wave][r16][j * 16 + 4 * g] = pk;
    }
#pragma unroll
    for (int ks = 0; ks < 2; ++ks) {
      bf16x8 pf = *(const bf16x8*)&Plds[wave][r16][ks * 32 + g * 8];
#pragma unroll
      for (int dj = 0; dj < 4; ++dj)
        o[dj] = __builtin_amdgcn_mfma_f32_16x16x32_bf16(pf, vf[ks][dj], o[dj], 0, 0, 0);
    }
  };

  bf16x8 kf0[2][4], kf1[2][4];
  loadK(0, kf0);
  int kt = 0;
  while (true) {
    body(kt, kf0, kf1);
    if (++kt > qt) break;
    body(kt, kf1, kf0);
    if (++kt > qt) break;
  }

  float le[4];
#pragma unroll
  for (int e = 0; e < 4; ++e) le[e] = __shfl(l, 4 * g + e, 64);
#pragma unroll
  for (int dj = 0; dj < 4; ++dj)
#pragma unroll
    for (int e = 0; e < 4; ++e) {
      float val = o[dj][e] / le[e];
      int t = qt * 64 + wave * 16 + 4 * g + e;
      yatt[((size_t)(bI * 2048 + t)) * 768 + h * 64 + dj * 16 + r16] = (__bf16)val;
    }
}

extern "C" void kernel_launch(void* const* d_in, const int* in_sizes, int n_in,
                              void* d_out, int out_size, void* d_ws, size_t ws_size,
                              hipStream_t stream) {
  (void)in_sizes; (void)n_in; (void)out_size; (void)ws_size;
  const float* x     = (const float*)d_in[0];
  const float* w_qkv = (const float*)d_in[1];
  const float* b_qkv = (const float*)d_in[2];
  const float* w_out = (const float*)d_in[3];
  const float* b_out = (const float*)d_in[4];
  float* out = (float*)d_out;

  char* ws = (char*)d_ws;
  __bf16* xb    = (__bf16*)(ws);              // [4096][768]
  __bf16* wqkvT = (__bf16*)(ws + 6291456);    // [2304][768]
  __bf16* woT   = (__bf16*)(ws + 9830400);    // [768][768]
  __bf16* qb    = (__bf16*)(ws + 11010048);   // [B,H,T,64]
  __bf16* kb    = (__bf16*)(ws + 17301504);   // [B,H,T,64]
  __bf16* vtb   = (__bf16*)(ws + 23592960);   // [B,H,64,T]  (V transposed)
  __bf16* yatt  = (__bf16*)(ws + 29884416);   // [4096][768]

  cvt_bf16_kernel<<<3072, 256, 0, stream>>>(x, xb, 786432);
  cvtT_bf16_kernel<<<dim3(72, 24), 256, 0, stream>>>(w_qkv, wqkvT, 768, 2304);
  cvtT_bf16_kernel<<<dim3(24, 24), 256, 0, stream>>>(w_out, woT, 768, 768);
  gemm_tn_kernel<0><<<dim3(18, 32), 256, 0, stream>>>(xb, wqkvT, b_qkv, nullptr,
                                                      qb, kb, vtb, 4096, 2304, 768);
  attn_kernel<<<768, 256, 0, stream>>>(qb, kb, vtb, yatt);
  gemm_tn_kernel<1><<<dim3(6, 32), 256, 0, stream>>>(yatt, woT, b_out, out,
                                                     nullptr, nullptr, nullptr, 4096, 768, 768);
}

// Round 4
// 154.599 us; speedup vs baseline: 1.8019x; 1.4023x over previous
//
#include <hip/hip_runtime.h>
#include <math.h>

// B=2, T=2048, D=768, H=12, HD=64
typedef __attribute__((ext_vector_type(8))) __bf16 bf16x8;
typedef __attribute__((ext_vector_type(4))) __bf16 bf16x4;
typedef __attribute__((ext_vector_type(4))) float f32x4;

#define GLOAD_LDS16(gsrc, ldst) \
  __builtin_amdgcn_global_load_lds((__attribute__((address_space(1))) const void*)(gsrc), \
                                   (__attribute__((address_space(3))) void*)(ldst), 16, 0, 0)

__global__ void cvt_bf16_kernel(const float* __restrict__ in, __bf16* __restrict__ out, int n4) {
  int i = blockIdx.x * 256 + threadIdx.x;
  if (i < n4) {
    float4 f = ((const float4*)in)[i];
    bf16x4 o;
    o[0] = (__bf16)f.x; o[1] = (__bf16)f.y; o[2] = (__bf16)f.z; o[3] = (__bf16)f.w;
    ((bf16x4*)out)[i] = o;
  }
}

// Tiled transpose-convert: out[C][R] = (bf16) in[R][C]. 32x32 tiles via LDS.
__global__ __launch_bounds__(256)
void cvtT_bf16_kernel(const float* __restrict__ in, __bf16* __restrict__ out, int R, int C) {
  __shared__ float t[32][33];
  int c0 = blockIdx.x * 32, r0 = blockIdx.y * 32;
  int tc = threadIdx.x & 31, tr = threadIdx.x >> 5;
#pragma unroll
  for (int i = 0; i < 4; ++i)
    t[tr + 8 * i][tc] = in[(size_t)(r0 + tr + 8 * i) * C + c0 + tc];
  __syncthreads();
#pragma unroll
  for (int i = 0; i < 4; ++i)
    out[(size_t)(c0 + tr + 8 * i) * R + r0 + tc] = (__bf16)t[tc][tr + 8 * i];
}

// TN GEMM: C[M][N] = A[M][K] * B[N][K]^T (+bias). 128x128 tile, BK=64, 4 waves.
template<int EPI>
__global__ __launch_bounds__(256)
void gemm_tn_kernel(const __bf16* __restrict__ A, const __bf16* __restrict__ Bm,
                    const float* __restrict__ bias, float* __restrict__ outF,
                    __bf16* __restrict__ qo, __bf16* __restrict__ ko, __bf16* __restrict__ vo,
                    int M, int N, int K) {
  const int lane = threadIdx.x & 63;
  const int wave = threadIdx.x >> 6;
  const int r16 = lane & 15, g = lane >> 4;
  const int mBase = blockIdx.y * 128, nBase = blockIdx.x * 128;
  __shared__ __align__(16) __bf16 lds[16384];

  f32x4 acc[4][4];
#pragma unroll
  for (int i = 0; i < 4; ++i)
#pragma unroll
    for (int j = 0; j < 4; ++j) acc[i][j] = (f32x4){0.f, 0.f, 0.f, 0.f};

  const int mw = (wave >> 1) * 4;
  const int nw = (wave & 1) * 4;

  for (int kt = 0; kt < K; kt += 64) {
#pragma unroll
    for (int i = 0; i < 8; ++i) {
      int seg = wave * 8 + i;
      int isB = seg >> 4, ks = (seg >> 3) & 1, t8 = seg & 7;
      int row = (isB ? nBase : mBase) + t8 * 16 + r16;
      const __bf16* src = (isB ? Bm : A) + (size_t)row * K + kt + ks * 32 + g * 8;
      GLOAD_LDS16(src, &lds[seg * 512]);
    }
    __syncthreads();
#pragma unroll
    for (int ks = 0; ks < 2; ++ks) {
      bf16x8 af[4], bfr[4];
#pragma unroll
      for (int i = 0; i < 4; ++i) af[i] = *(const bf16x8*)&lds[((ks * 8 + mw + i) * 64 + lane) * 8];
#pragma unroll
      for (int j = 0; j < 4; ++j) bfr[j] = *(const bf16x8*)&lds[((16 + ks * 8 + nw + j) * 64 + lane) * 8];
#pragma unroll
      for (int i = 0; i < 4; ++i)
#pragma unroll
        for (int j = 0; j < 4; ++j)
          acc[i][j] = __builtin_amdgcn_mfma_f32_16x16x32_bf16(af[i], bfr[j], acc[i][j], 0, 0, 0);
    }
    __syncthreads();
  }

#pragma unroll
  for (int i = 0; i < 4; ++i) {
#pragma unroll
    for (int j = 0; j < 4; ++j) {
      int c = nBase + (nw + j) * 16 + r16;
      float bb = bias[c];
#pragma unroll
      for (int e = 0; e < 4; ++e) {
        int r = mBase + (mw + i) * 16 + g * 4 + e;
        float val = acc[i][j][e] + bb;
        if (EPI == 0) {
          int which = c / 768;             // 0:q 1:k 2:v
          int cc = c - which * 768;
          int hh = cc >> 6, dd = cc & 63;
          int bI = r >> 11, tt = r & 2047;
          if (which == 0) {
            // fold 1/sqrt(64) * log2(e) into q (softmax runs in exp2 space)
            qo[(((size_t)(bI * 12 + hh)) * 2048 + tt) * 64 + dd] = (__bf16)(val * 0.180336880f);
          } else if (which == 1) {
            ko[(((size_t)(bI * 12 + hh)) * 2048 + tt) * 64 + dd] = (__bf16)val;
          } else {
            vo[(((size_t)(bI * 12 + hh)) * 64 + dd) * 2048 + tt] = (__bf16)val;  // V^T [B,H,64,T]
          }
        } else {
          outF[(size_t)r * N + c] = val;
        }
      }
    }
  }
}

// Flash attention, causal, swapped-QK^T, O^T accumulation.
// K/V tiles double-buffered in LDS via global_load_lds (XOR-swizzled through
// pre-swizzled global source, rule 21); one barrier/iter; stage(kt+1) issued
// after the barrier so it overlaps compute(kt) and drains at the next barrier.
// q is lane-local (q = lane&15): softmax m/l/alpha are per-lane scalars.
__global__ __launch_bounds__(256)
void attn_kernel(const __bf16* __restrict__ qg, const __bf16* __restrict__ kg,
                 const __bf16* __restrict__ vtg, __bf16* __restrict__ yatt) {
  const int id = blockIdx.x;
  const int chunk = id & 7, within = id >> 3;   // XCD chunk = 3 heads (L2-resident K/V)
  const int bh = chunk * 3 + (within >> 5);
  const int qt = 31 - (within & 31);            // heaviest q-tiles dispatch first
  const int lane = threadIdx.x & 63, wave = threadIdx.x >> 6;
  const int r16 = lane & 15, g = lane >> 4;
  const int bI = bh / 12, h = bh - bI * 12;
  const size_t headoff = (size_t)bh * 2048 * 64;
  const __bf16* Q = qg + headoff;
  const __bf16* Kh = kg + headoff;
  const __bf16* VT = vtg + headoff;             // [64][2048]

  __shared__ __align__(16) __bf16 Kbuf[2][4096];   // [64 rows][8 chunks] swizzled, 8KB each
  __shared__ __align__(16) __bf16 Vbuf[2][4096];
  __shared__ __align__(16) __bf16 Plds[4][16][72];

  const int tq = qt * 64 + wave * 16 + r16;
  bf16x8 qf[2];
  qf[0] = *(const bf16x8*)&Q[(size_t)tq * 64 + g * 8];
  qf[1] = *(const bf16x8*)&Q[(size_t)tq * 64 + 32 + g * 8];

  // stage geometry: segment s = i*4+wave holds chunks c = s*64+lane;
  // physical chunk c -> source logical chunk cl = (c&7) ^ (row&7), row = c>>3
  int srow[2], scl[2];
#pragma unroll
  for (int i = 0; i < 2; ++i) {
    int c = (i * 4 + wave) * 64 + lane;
    srow[i] = c >> 3;
    scl[i] = (c & 7) ^ (srow[i] & 7);
  }

  f32x4 o[4];
#pragma unroll
  for (int j = 0; j < 4; ++j) o[j] = (f32x4){0.f, 0.f, 0.f, 0.f};
  float m = -INFINITY, l = 0.f;   // for q-row r16, log2 space

  // prologue stage of tile 0
#pragma unroll
  for (int i = 0; i < 2; ++i) {
    GLOAD_LDS16(&Kh[(size_t)srow[i] * 64 + scl[i] * 8], &Kbuf[0][(i * 4 + wave) * 512]);
    GLOAD_LDS16(&VT[(size_t)srow[i] * 2048 + scl[i] * 8], &Vbuf[0][(i * 4 + wave) * 512]);
  }

  for (int kt = 0; kt <= qt; ++kt) {
    const int cur = kt & 1;
    __syncthreads();                 // drains staging of buf[cur]; guards buf reuse
    if (kt < qt) {
      const int nxt = cur ^ 1;
#pragma unroll
      for (int i = 0; i < 2; ++i) {
        GLOAD_LDS16(&Kh[(size_t)((kt + 1) * 64 + srow[i]) * 64 + scl[i] * 8],
                    &Kbuf[nxt][(i * 4 + wave) * 512]);
        GLOAD_LDS16(&VT[(size_t)srow[i] * 2048 + (kt + 1) * 64 + scl[i] * 8],
                    &Vbuf[nxt][(i * 4 + wave) * 512]);
      }
    }
    // QK^T: S^T[k][q] = K·Q^T
    f32x4 st[4];
#pragma unroll
    for (int j = 0; j < 4; ++j) st[j] = (f32x4){0.f, 0.f, 0.f, 0.f};
    __builtin_amdgcn_s_setprio(1);
#pragma unroll
    for (int ks = 0; ks < 2; ++ks)
#pragma unroll
      for (int j = 0; j < 4; ++j) {
        int row = j * 16 + r16;
        int cp = (ks * 4 + g) ^ (row & 7);
        bf16x8 kf = *(const bf16x8*)&Kbuf[cur][(row * 8 + cp) * 8];
        st[j] = __builtin_amdgcn_mfma_f32_16x16x32_bf16(kf, qf[ks], st[j], 0, 0, 0);
      }
    __builtin_amdgcn_s_setprio(0);
    // V fragments early: ds_reads in flight under softmax
    bf16x8 vf[2][4];
#pragma unroll
    for (int ks = 0; ks < 2; ++ks)
#pragma unroll
      for (int dj = 0; dj < 4; ++dj) {
        int row = dj * 16 + r16;
        int cp = (ks * 4 + g) ^ (row & 7);
        vf[ks][dj] = *(const bf16x8*)&Vbuf[cur][(row * 8 + cp) * 8];
      }
    if (kt == qt) {  // causal: k = j*16+4g+e, q = wave*16+r16 (tile-local)
#pragma unroll
      for (int j = 0; j < 4; ++j)
#pragma unroll
        for (int e = 0; e < 4; ++e)
          if (j * 16 + 4 * g + e > wave * 16 + r16) st[j][e] = -INFINITY;
    }
    // online softmax in exp2 space; lane owns q-row r16
    float mt = -INFINITY;
#pragma unroll
    for (int j = 0; j < 4; ++j)
#pragma unroll
      for (int e = 0; e < 4; ++e) mt = fmaxf(mt, st[j][e]);
    mt = fmaxf(mt, __shfl_xor(mt, 16, 64));
    mt = fmaxf(mt, __shfl_xor(mt, 32, 64));
    float mn = fmaxf(m, mt);
    float alpha = exp2f(m - mn);
    m = mn;
    float ls = 0.f;
#pragma unroll
    for (int j = 0; j < 4; ++j)
#pragma unroll
      for (int e = 0; e < 4; ++e) {
        float p = exp2f(st[j][e] - mn);
        st[j][e] = p;
        ls += p;
      }
    ls += __shfl_xor(ls, 16, 64);
    ls += __shfl_xor(ls, 32, 64);
    l = l * alpha + ls;
#pragma unroll
    for (int dj = 0; dj < 4; ++dj)
#pragma unroll
      for (int e = 0; e < 4; ++e) o[dj][e] *= alpha;   // per-lane alpha (own q)
    // P -> per-wave LDS strip (same-wave RAW; DS pipe is in-order per wave)
#pragma unroll
    for (int j = 0; j < 4; ++j) {
      bf16x4 pk;
#pragma unroll
      for (int e = 0; e < 4; ++e) pk[e] = (__bf16)st[j][e];
      *(bf16x4*)&Plds[wave][r16][j * 16 + 4 * g] = pk;
    }
    // PV: O^T = V^T · P^T
    __builtin_amdgcn_s_setprio(1);
#pragma unroll
    for (int ks = 0; ks < 2; ++ks) {
      bf16x8 pf = *(const bf16x8*)&Plds[wave][r16][ks * 32 + g * 8];
#pragma unroll
      for (int dj = 0; dj < 4; ++dj)
        o[dj] = __builtin_amdgcn_mfma_f32_16x16x32_bf16(vf[ks][dj], pf, o[dj], 0, 0, 0);
    }
    __builtin_amdgcn_s_setprio(0);
  }

  // epilogue: per-lane l (own q); O^T[d][q]: d = dj*16 + 4g + e, q = r16
  float inv = 1.0f / l;
  int t = qt * 64 + wave * 16 + r16;
#pragma unroll
  for (int dj = 0; dj < 4; ++dj) {
    bf16x4 ov;
#pragma unroll
    for (int e = 0; e < 4; ++e) ov[e] = (__bf16)(o[dj][e] * inv);
    *(bf16x4*)&yatt[((size_t)(bI * 2048 + t)) * 768 + h * 64 + dj * 16 + 4 * g] = ov;
  }
}

extern "C" void kernel_launch(void* const* d_in, const int* in_sizes, int n_in,
                              void* d_out, int out_size, void* d_ws, size_t ws_size,
                              hipStream_t stream) {
  (void)in_sizes; (void)n_in; (void)out_size; (void)ws_size;
  const float* x     = (const float*)d_in[0];
  const float* w_qkv = (const float*)d_in[1];
  const float* b_qkv = (const float*)d_in[2];
  const float* w_out = (const float*)d_in[3];
  const float* b_out = (const float*)d_in[4];
  float* out = (float*)d_out;

  char* ws = (char*)d_ws;
  __bf16* xb    = (__bf16*)(ws);              // [4096][768]
  __bf16* wqkvT = (__bf16*)(ws + 6291456);    // [2304][768]
  __bf16* woT   = (__bf16*)(ws + 9830400);    // [768][768]
  __bf16* qb    = (__bf16*)(ws + 11010048);   // [B,H,T,64]  (pre-scaled by 0.125*log2e)
  __bf16* kb    = (__bf16*)(ws + 17301504);   // [B,H,T,64]
  __bf16* vtb   = (__bf16*)(ws + 23592960);   // [B,H,64,T]  (V transposed)
  __bf16* yatt  = (__bf16*)(ws + 29884416);   // [4096][768]

  cvt_bf16_kernel<<<3072, 256, 0, stream>>>(x, xb, 786432);
  cvtT_bf16_kernel<<<dim3(72, 24), 256, 0, stream>>>(w_qkv, wqkvT, 768, 2304);
  cvtT_bf16_kernel<<<dim3(24, 24), 256, 0, stream>>>(w_out, woT, 768, 768);
  gemm_tn_kernel<0><<<dim3(18, 32), 256, 0, stream>>>(xb, wqkvT, b_qkv, nullptr,
                                                      qb, kb, vtb, 4096, 2304, 768);
  attn_kernel<<<768, 256, 0, stream>>>(qb, kb, vtb, yatt);
  gemm_tn_kernel<1><<<dim3(6, 32), 256, 0, stream>>>(yatt, woT, b_out, out,
                                                     nullptr, nullptr, nullptr, 4096, 768, 768);
}

// Round 5
// 140.118 us; speedup vs baseline: 1.9881x; 1.1034x over previous
//
#include <hip/hip_runtime.h>
#include <math.h>

// B=2, T=2048, D=768, H=12, HD=64
typedef __attribute__((ext_vector_type(8))) __bf16 bf16x8;
typedef __attribute__((ext_vector_type(4))) __bf16 bf16x4;
typedef __attribute__((ext_vector_type(4))) float f32x4;

#define GLOAD_LDS16(gsrc, ldst) \
  __builtin_amdgcn_global_load_lds((__attribute__((address_space(1))) const void*)(gsrc), \
                                   (__attribute__((address_space(3))) void*)(ldst), 16, 0, 0)

__global__ void cvt_bf16_kernel(const float* __restrict__ in, __bf16* __restrict__ out, int n4) {
  int i = blockIdx.x * 256 + threadIdx.x;
  if (i < n4) {
    float4 f = ((const float4*)in)[i];
    bf16x4 o;
    o[0] = (__bf16)f.x; o[1] = (__bf16)f.y; o[2] = (__bf16)f.z; o[3] = (__bf16)f.w;
    ((bf16x4*)out)[i] = o;
  }
}

// Tiled transpose-convert: out[C][R] = (bf16) in[R][C]. 32x32 tiles via LDS.
__global__ __launch_bounds__(256)
void cvtT_bf16_kernel(const float* __restrict__ in, __bf16* __restrict__ out, int R, int C) {
  __shared__ float t[32][33];
  int c0 = blockIdx.x * 32, r0 = blockIdx.y * 32;
  int tc = threadIdx.x & 31, tr = threadIdx.x >> 5;
#pragma unroll
  for (int i = 0; i < 4; ++i)
    t[tr + 8 * i][tc] = in[(size_t)(r0 + tr + 8 * i) * C + c0 + tc];
  __syncthreads();
#pragma unroll
  for (int i = 0; i < 4; ++i)
    out[(size_t)(c0 + tr + 8 * i) * R + r0 + tc] = (__bf16)t[tc][tr + 8 * i];
}

// TN GEMM: C[M][N] = A[M][K] * B[N][K]^T (+bias). 128x128 tile, BK=64, 4 waves.
// T3-min pipeline: LDS double-buffered; per iter {barrier; stage(t+1,nxt); compute(cur)}
// -> staging overlaps MFMA, one barrier per K-step, vmcnt drains at next barrier.
template<int EPI>
__global__ __launch_bounds__(256)
void gemm_tn_kernel(const __bf16* __restrict__ A, const __bf16* __restrict__ Bm,
                    const float* __restrict__ bias, float* __restrict__ outF,
                    __bf16* __restrict__ qo, __bf16* __restrict__ ko, __bf16* __restrict__ vo,
                    int M, int N, int K) {
  const int lane = threadIdx.x & 63;
  const int wave = threadIdx.x >> 6;
  const int r16 = lane & 15, g = lane >> 4;
  const int mBase = blockIdx.y * 128, nBase = blockIdx.x * 128;
  __shared__ __align__(16) __bf16 lds[2][16384];   // 2 x (16KB A + 16KB B)

  f32x4 acc[4][4];
#pragma unroll
  for (int i = 0; i < 4; ++i)
#pragma unroll
    for (int j = 0; j < 4; ++j) acc[i][j] = (f32x4){0.f, 0.f, 0.f, 0.f};

  const int mw = (wave >> 1) * 4;
  const int nw = (wave & 1) * 4;

  // per-thread staging geometry (8 segments of 64 chunks x 16B per buffer half)
  auto stage = [&](int kt, int b) {
#pragma unroll
    for (int i = 0; i < 8; ++i) {
      int seg = wave * 8 + i;
      int isB = seg >> 4, ks = (seg >> 3) & 1, t8 = seg & 7;
      int row = (isB ? nBase : mBase) + t8 * 16 + r16;
      const __bf16* src = (isB ? Bm : A) + (size_t)row * K + kt + ks * 32 + g * 8;
      GLOAD_LDS16(src, &lds[b][seg * 512]);
    }
  };

  const int nt = K >> 6;
  stage(0, 0);
  for (int t = 0; t < nt; ++t) {
    const int cur = t & 1;
    __syncthreads();                       // drains stage(cur); syncs buffer reuse
    if (t + 1 < nt) stage((t + 1) << 6, cur ^ 1);
#pragma unroll
    for (int ks = 0; ks < 2; ++ks) {
      bf16x8 af[4], bfr[4];
#pragma unroll
      for (int i = 0; i < 4; ++i) af[i] = *(const bf16x8*)&lds[cur][((ks * 8 + mw + i) * 64 + lane) * 8];
#pragma unroll
      for (int j = 0; j < 4; ++j) bfr[j] = *(const bf16x8*)&lds[cur][((16 + ks * 8 + nw + j) * 64 + lane) * 8];
#pragma unroll
      for (int i = 0; i < 4; ++i)
#pragma unroll
        for (int j = 0; j < 4; ++j)
          acc[i][j] = __builtin_amdgcn_mfma_f32_16x16x32_bf16(af[i], bfr[j], acc[i][j], 0, 0, 0);
    }
  }

#pragma unroll
  for (int i = 0; i < 4; ++i) {
#pragma unroll
    for (int j = 0; j < 4; ++j) {
      int c = nBase + (nw + j) * 16 + r16;
      float bb = bias[c];
#pragma unroll
      for (int e = 0; e < 4; ++e) {
        int r = mBase + (mw + i) * 16 + g * 4 + e;
        float val = acc[i][j][e] + bb;
        if (EPI == 0) {
          int which = c / 768;             // 0:q 1:k 2:v
          int cc = c - which * 768;
          int hh = cc >> 6, dd = cc & 63;
          int bI = r >> 11, tt = r & 2047;
          if (which == 0) {
            // fold 1/sqrt(64) * log2(e) into q (softmax runs in exp2 space)
            qo[(((size_t)(bI * 12 + hh)) * 2048 + tt) * 64 + dd] = (__bf16)(val * 0.180336880f);
          } else if (which == 1) {
            ko[(((size_t)(bI * 12 + hh)) * 2048 + tt) * 64 + dd] = (__bf16)val;
          } else {
            vo[(((size_t)(bI * 12 + hh)) * 64 + dd) * 2048 + tt] = (__bf16)val;  // V^T [B,H,64,T]
          }
        } else {
          outF[(size_t)r * N + c] = val;
        }
      }
    }
  }
}

// Flash attention, causal, swapped-QK^T, O^T accumulation, CAUSAL-PAIRED tiles.
// 32-row q-tiles; block (128 thr = 2 waves) owns pair (a, 63-a): total K-tiles
// K_a + K_p = 33 constant -> 768 perfectly uniform blocks = exactly 3/CU.
// K/V staged in LDS (dbuf, XOR-swizzled via pre-swizzled source); kf/vf fragment
// reads SHARED by both q-tiles of the pair. One barrier per K-tile.
__global__ __launch_bounds__(128)
void attn_kernel(const __bf16* __restrict__ qg, const __bf16* __restrict__ kg,
                 const __bf16* __restrict__ vtg, __bf16* __restrict__ yatt) {
  const int id = blockIdx.x;
  const int chunk = id & 7, within = id >> 3;   // XCD chunk = 3 heads (L2-resident K/V)
  const int bh = chunk * 3 + (within >> 5);
  const int a = within & 31, p = 63 - a;        // paired 32-row q-tiles
  const int Ka = (a >> 1) + 1, Kp = (p >> 1) + 1;
  const int lane = threadIdx.x & 63, wave = threadIdx.x >> 6;  // wave in {0,1}
  const int r16 = lane & 15, g = lane >> 4;
  const int bI = bh / 12, h = bh - bI * 12;
  const size_t headoff = (size_t)bh * 2048 * 64;
  const __bf16* Q = qg + headoff;
  const __bf16* Kh = kg + headoff;
  const __bf16* VT = vtg + headoff;             // [64][2048]

  __shared__ __align__(16) __bf16 Kbuf[2][4096];   // [64 k-rows][8 chunks] swizzled
  __shared__ __align__(16) __bf16 Vbuf[2][4096];   // [64 d-rows][8 chunks] swizzled
  __shared__ __align__(16) __bf16 Plds[2][2][16][72];  // [wave][slot][q][k]

  const int rowA = a * 32 + wave * 16 + r16;     // this lane's q-row (tile a)
  const int rowP = p * 32 + wave * 16 + r16;     // and tile p
  bf16x8 qfa[2], qfp[2];
#pragma unroll
  for (int ks = 0; ks < 2; ++ks) {
    qfa[ks] = *(const bf16x8*)&Q[(size_t)rowA * 64 + ks * 32 + g * 8];
    qfp[ks] = *(const bf16x8*)&Q[(size_t)rowP * 64 + ks * 32 + g * 8];
  }

  // staging: 4 chunks/thread/buffer; chunk c = (i*2+wave)*64+lane; row=c>>3,
  // source col-chunk = (c&7)^(row&7)  (pre-swizzled source, linear LDS dest)
  int srow[4], scl[4];
#pragma unroll
  for (int i = 0; i < 4; ++i) {
    int c = (i * 2 + wave) * 64 + lane;
    srow[i] = c >> 3;
    scl[i] = (c & 7) ^ (srow[i] & 7);
  }
  auto stage = [&](int kt, int b) {
#pragma unroll
    for (int i = 0; i < 4; ++i) {
      GLOAD_LDS16(&Kh[(size_t)(kt * 64 + srow[i]) * 64 + scl[i] * 8], &Kbuf[b][(i * 2 + wave) * 512]);
      GLOAD_LDS16(&VT[(size_t)srow[i] * 2048 + kt * 64 + scl[i] * 8], &Vbuf[b][(i * 2 + wave) * 512]);
    }
  };

  f32x4 oa[4], op[4];
#pragma unroll
  for (int j = 0; j < 4; ++j) { oa[j] = (f32x4){0.f,0.f,0.f,0.f}; op[j] = (f32x4){0.f,0.f,0.f,0.f}; }
  float ma = -INFINITY, la = 0.f, mp = -INFINITY, lp = 0.f;

  // softmax + PV for one tile (st consumed; o/m/l updated); slot picks Plds strip
  auto process = [&](f32x4 (&st)[4], float& m, float& l, f32x4 (&o)[4],
                     bool domask, int rowq, int kt, const bf16x8 (&vf)[2][4], int slot) {
    if (domask) {
#pragma unroll
      for (int j = 0; j < 4; ++j)
#pragma unroll
        for (int e = 0; e < 4; ++e)
          if (kt * 64 + j * 16 + 4 * g + e > rowq) st[j][e] = -INFINITY;
    }
    float mt = -INFINITY;
#pragma unroll
    for (int j = 0; j < 4; ++j)
#pragma unroll
      for (int e = 0; e < 4; ++e) mt = fmaxf(mt, st[j][e]);
    mt = fmaxf(mt, __shfl_xor(mt, 16, 64));
    mt = fmaxf(mt, __shfl_xor(mt, 32, 64));
    float mn = fmaxf(m, mt);
    float alpha = exp2f(m - mn);
    m = mn;
    float ls = 0.f;
#pragma unroll
    for (int j = 0; j < 4; ++j)
#pragma unroll
      for (int e = 0; e < 4; ++e) {
        float pv = exp2f(st[j][e] - mn);
        st[j][e] = pv;
        ls += pv;
      }
    ls += __shfl_xor(ls, 16, 64);
    ls += __shfl_xor(ls, 32, 64);
    l = l * alpha + ls;
#pragma unroll
    for (int dj = 0; dj < 4; ++dj)
#pragma unroll
      for (int e = 0; e < 4; ++e) o[dj][e] *= alpha;
#pragma unroll
    for (int j = 0; j < 4; ++j) {
      bf16x4 pk;
#pragma unroll
      for (int e = 0; e < 4; ++e) pk[e] = (__bf16)st[j][e];
      *(bf16x4*)&Plds[wave][slot][r16][j * 16 + 4 * g] = pk;
    }
#pragma unroll
    for (int ks = 0; ks < 2; ++ks) {
      bf16x8 pf = *(const bf16x8*)&Plds[wave][slot][r16][ks * 32 + g * 8];
#pragma unroll
      for (int dj = 0; dj < 4; ++dj)
        o[dj] = __builtin_amdgcn_mfma_f32_16x16x32_bf16(vf[ks][dj], pf, o[dj], 0, 0, 0);
    }
  };

  stage(0, 0);
  for (int kt = 0; kt < Kp; ++kt) {
    const int cur = kt & 1;
    __syncthreads();                       // drains stage(cur); guards reuse
    if (kt + 1 < Kp) stage(kt + 1, cur ^ 1);
    const bool dualA = (kt < Ka);
    // QK^T both tiles, kf shared
    f32x4 stp[4], sta[4];
#pragma unroll
    for (int j = 0; j < 4; ++j) { stp[j] = (f32x4){0.f,0.f,0.f,0.f}; sta[j] = (f32x4){0.f,0.f,0.f,0.f}; }
    __builtin_amdgcn_s_setprio(1);
#pragma unroll
    for (int ks = 0; ks < 2; ++ks)
#pragma unroll
      for (int j = 0; j < 4; ++j) {
        int row = j * 16 + r16;
        int cp = (ks * 4 + g) ^ (row & 7);
        bf16x8 kf = *(const bf16x8*)&Kbuf[cur][(row * 8 + cp) * 8];
        stp[j] = __builtin_amdgcn_mfma_f32_16x16x32_bf16(kf, qfp[ks], stp[j], 0, 0, 0);
        if (dualA) sta[j] = __builtin_amdgcn_mfma_f32_16x16x32_bf16(kf, qfa[ks], sta[j], 0, 0, 0);
      }
    __builtin_amdgcn_s_setprio(0);
    // V fragments (shared by both tiles), in flight under softmax
    bf16x8 vf[2][4];
#pragma unroll
    for (int ks = 0; ks < 2; ++ks)
#pragma unroll
      for (int dj = 0; dj < 4; ++dj) {
        int row = dj * 16 + r16;
        int cp = (ks * 4 + g) ^ (row & 7);
        vf[ks][dj] = *(const bf16x8*)&Vbuf[cur][(row * 8 + cp) * 8];
      }
    process(stp, mp, lp, op, kt == Kp - 1, rowP, kt, vf, 0);
    if (dualA) process(sta, ma, la, oa, kt == Ka - 1, rowA, kt, vf, 1);
  }

  // epilogue: O^T[d][q]: per-lane q = r16, d = dj*16 + 4g + e (4 contiguous)
  float invp = 1.0f / lp, inva = 1.0f / la;
#pragma unroll
  for (int dj = 0; dj < 4; ++dj) {
    bf16x4 ovp, ova;
#pragma unroll
    for (int e = 0; e < 4; ++e) { ovp[e] = (__bf16)(op[dj][e] * invp); ova[e] = (__bf16)(oa[dj][e] * inva); }
    *(bf16x4*)&yatt[((size_t)(bI * 2048 + rowP)) * 768 + h * 64 + dj * 16 + 4 * g] = ovp;
    *(bf16x4*)&yatt[((size_t)(bI * 2048 + rowA)) * 768 + h * 64 + dj * 16 + 4 * g] = ova;
  }
}

extern "C" void kernel_launch(void* const* d_in, const int* in_sizes, int n_in,
                              void* d_out, int out_size, void* d_ws, size_t ws_size,
                              hipStream_t stream) {
  (void)in_sizes; (void)n_in; (void)out_size; (void)ws_size;
  const float* x     = (const float*)d_in[0];
  const float* w_qkv = (const float*)d_in[1];
  const float* b_qkv = (const float*)d_in[2];
  const float* w_out = (const float*)d_in[3];
  const float* b_out = (const float*)d_in[4];
  float* out = (float*)d_out;

  char* ws = (char*)d_ws;
  __bf16* xb    = (__bf16*)(ws);              // [4096][768]
  __bf16* wqkvT = (__bf16*)(ws + 6291456);    // [2304][768]
  __bf16* woT   = (__bf16*)(ws + 9830400);    // [768][768]
  __bf16* qb    = (__bf16*)(ws + 11010048);   // [B,H,T,64]  (pre-scaled by 0.125*log2e)
  __bf16* kb    = (__bf16*)(ws + 17301504);   // [B,H,T,64]
  __bf16* vtb   = (__bf16*)(ws + 23592960);   // [B,H,64,T]  (V transposed)
  __bf16* yatt  = (__bf16*)(ws + 29884416);   // [4096][768]

  cvt_bf16_kernel<<<3072, 256, 0, stream>>>(x, xb, 786432);
  cvtT_bf16_kernel<<<dim3(72, 24), 256, 0, stream>>>(w_qkv, wqkvT, 768, 2304);
  cvtT_bf16_kernel<<<dim3(24, 24), 256, 0, stream>>>(w_out, woT, 768, 768);
  gemm_tn_kernel<0><<<dim3(18, 32), 256, 0, stream>>>(xb, wqkvT, b_qkv, nullptr,
                                                      qb, kb, vtb, 4096, 2304, 768);
  attn_kernel<<<768, 128, 0, stream>>>(qb, kb, vtb, yatt);
  gemm_tn_kernel<1><<<dim3(6, 32), 256, 0, stream>>>(yatt, woT, b_out, out,
                                                     nullptr, nullptr, nullptr, 4096, 768, 768);
}

// Round 6
// 134.751 us; speedup vs baseline: 2.0673x; 1.0398x over previous
//
#include <hip/hip_runtime.h>
#include <math.h>

// B=2, T=2048, D=768, H=12, HD=64
typedef __attribute__((ext_vector_type(8))) __bf16 bf16x8;
typedef __attribute__((ext_vector_type(4))) __bf16 bf16x4;
typedef __attribute__((ext_vector_type(4))) float f32x4;

#define GLOAD_LDS16(gsrc, ldst) \
  __builtin_amdgcn_global_load_lds((__attribute__((address_space(1))) const void*)(gsrc), \
                                   (__attribute__((address_space(3))) void*)(ldst), 16, 0, 0)

__device__ __forceinline__ float fexp2(float x) {
#if __has_builtin(__builtin_amdgcn_exp2f)
  return __builtin_amdgcn_exp2f(x);   // raw v_exp_f32 (input already in log2 space)
#else
  return exp2f(x);
#endif
}

__global__ void cvt_bf16_kernel(const float* __restrict__ in, __bf16* __restrict__ out, int n4) {
  int i = blockIdx.x * 256 + threadIdx.x;
  if (i < n4) {
    float4 f = ((const float4*)in)[i];
    bf16x4 o;
    o[0] = (__bf16)f.x; o[1] = (__bf16)f.y; o[2] = (__bf16)f.z; o[3] = (__bf16)f.w;
    ((bf16x4*)out)[i] = o;
  }
}

// Tiled transpose-convert: out[C][R] = (bf16) in[R][C]. 32x32 tiles via LDS.
__global__ __launch_bounds__(256)
void cvtT_bf16_kernel(const float* __restrict__ in, __bf16* __restrict__ out, int R, int C) {
  __shared__ float t[32][33];
  int c0 = blockIdx.x * 32, r0 = blockIdx.y * 32;
  int tc = threadIdx.x & 31, tr = threadIdx.x >> 5;
#pragma unroll
  for (int i = 0; i < 4; ++i)
    t[tr + 8 * i][tc] = in[(size_t)(r0 + tr + 8 * i) * C + c0 + tc];
  __syncthreads();
#pragma unroll
  for (int i = 0; i < 4; ++i)
    out[(size_t)(c0 + tr + 8 * i) * R + r0 + tc] = (__bf16)t[tc][tr + 8 * i];
}

// TN GEMM: C[M][N] = A[M][K] * B[N][K]^T (+bias). 128x128 tile, BK=32, 4 waves.
// BK=32 dbuf = 32KB LDS -> 4-5 blocks/CU (vs 2 at BK=64): cross-block overlap
// covers the per-iter barrier. Per iter {barrier; stage(t+1,nxt); compute(cur)}.
template<int EPI>
__global__ __launch_bounds__(256, 4)
void gemm_tn_kernel(const __bf16* __restrict__ A, const __bf16* __restrict__ Bm,
                    const float* __restrict__ bias, float* __restrict__ outF,
                    __bf16* __restrict__ qo, __bf16* __restrict__ ko, __bf16* __restrict__ vo,
                    int M, int N, int K) {
  const int lane = threadIdx.x & 63;
  const int wave = threadIdx.x >> 6;
  const int r16 = lane & 15, g = lane >> 4;
  const int mBase = blockIdx.y * 128, nBase = blockIdx.x * 128;
  __shared__ __align__(16) __bf16 lds[2][8192];   // 2 x (8KB A + 8KB B)

  f32x4 acc[4][4];
#pragma unroll
  for (int i = 0; i < 4; ++i)
#pragma unroll
    for (int j = 0; j < 4; ++j) acc[i][j] = (f32x4){0.f, 0.f, 0.f, 0.f};

  const int mw = (wave >> 1) * 4;
  const int nw = (wave & 1) * 4;

  // 16 segments of 64 lanes x 16B; segs 0..7 = A row-tiles, 8..15 = B row-tiles
  auto stage = [&](int ke, int b) {
#pragma unroll
    for (int i = 0; i < 4; ++i) {
      int seg = wave * 4 + i;
      int isB = seg >> 3, t8 = seg & 7;
      int row = (isB ? nBase : mBase) + t8 * 16 + r16;
      const __bf16* src = (isB ? Bm : A) + (size_t)row * K + ke + g * 8;
      GLOAD_LDS16(src, &lds[b][seg * 512]);
    }
  };

  const int nt = K >> 5;
  stage(0, 0);
  for (int t = 0; t < nt; ++t) {
    const int cur = t & 1;
    __syncthreads();                       // drains stage(cur); syncs buffer reuse
    if (t + 1 < nt) stage((t + 1) << 5, cur ^ 1);
    bf16x8 af[4], bfr[4];
#pragma unroll
    for (int i = 0; i < 4; ++i) af[i] = *(const bf16x8*)&lds[cur][((mw + i) * 64 + lane) * 8];
#pragma unroll
    for (int j = 0; j < 4; ++j) bfr[j] = *(const bf16x8*)&lds[cur][((8 + nw + j) * 64 + lane) * 8];
    __builtin_amdgcn_s_setprio(1);
#pragma unroll
    for (int i = 0; i < 4; ++i)
#pragma unroll
      for (int j = 0; j < 4; ++j)
        acc[i][j] = __builtin_amdgcn_mfma_f32_16x16x32_bf16(af[i], bfr[j], acc[i][j], 0, 0, 0);
    __builtin_amdgcn_s_setprio(0);
  }

#pragma unroll
  for (int i = 0; i < 4; ++i) {
#pragma unroll
    for (int j = 0; j < 4; ++j) {
      int c = nBase + (nw + j) * 16 + r16;
      float bb = bias[c];
#pragma unroll
      for (int e = 0; e < 4; ++e) {
        int r = mBase + (mw + i) * 16 + g * 4 + e;
        float val = acc[i][j][e] + bb;
        if (EPI == 0) {
          int which = c / 768;             // 0:q 1:k 2:v
          int cc = c - which * 768;
          int hh = cc >> 6, dd = cc & 63;
          int bI = r >> 11, tt = r & 2047;
          if (which == 0) {
            // fold 1/sqrt(64) * log2(e) into q (softmax runs in exp2 space)
            qo[(((size_t)(bI * 12 + hh)) * 2048 + tt) * 64 + dd] = (__bf16)(val * 0.180336880f);
          } else if (which == 1) {
            ko[(((size_t)(bI * 12 + hh)) * 2048 + tt) * 64 + dd] = (__bf16)val;
          } else {
            vo[(((size_t)(bI * 12 + hh)) * 64 + dd) * 2048 + tt] = (__bf16)val;  // V^T [B,H,64,T]
          }
        } else {
          outF[(size_t)r * N + c] = val;
        }
      }
    }
  }
}

// Flash attention, causal, swapped-QK^T, O^T accumulation, CAUSAL-PAIRED tiles.
// 32-row q-tiles; block (128 thr = 2 waves) owns pair (a, 63-a): K_a+K_p = 33
// constant -> 768 uniform blocks. LDS 36.5KB -> 4 blocks/CU (8 waves).
// Defer-max (THR=8): skip O-rescale when the running max is stable.
__global__ __launch_bounds__(128, 2)
void attn_kernel(const __bf16* __restrict__ qg, const __bf16* __restrict__ kg,
                 const __bf16* __restrict__ vtg, __bf16* __restrict__ yatt) {
  const int id = blockIdx.x;
  const int chunk = id & 7, within = id >> 3;   // XCD chunk = 3 heads (L2-resident K/V)
  const int bh = chunk * 3 + (within >> 5);
  const int a = within & 31, p = 63 - a;        // paired 32-row q-tiles
  const int Ka = (a >> 1) + 1, Kp = (p >> 1) + 1;
  const int lane = threadIdx.x & 63, wave = threadIdx.x >> 6;  // wave in {0,1}
  const int r16 = lane & 15, g = lane >> 4;
  const int bI = bh / 12, h = bh - bI * 12;
  const size_t headoff = (size_t)bh * 2048 * 64;
  const __bf16* Q = qg + headoff;
  const __bf16* Kh = kg + headoff;
  const __bf16* VT = vtg + headoff;             // [64][2048]

  __shared__ __align__(16) __bf16 Kbuf[2][4096];   // [64 k-rows][8 chunks] swizzled
  __shared__ __align__(16) __bf16 Vbuf[2][4096];   // [64 d-rows][8 chunks] swizzled
  __shared__ __align__(16) __bf16 Plds[2][16][72]; // [wave][q][k] single strip (seq. reuse)

  const int rowA = a * 32 + wave * 16 + r16;
  const int rowP = p * 32 + wave * 16 + r16;
  bf16x8 qfa[2], qfp[2];
#pragma unroll
  for (int ks = 0; ks < 2; ++ks) {
    qfa[ks] = *(const bf16x8*)&Q[(size_t)rowA * 64 + ks * 32 + g * 8];
    qfp[ks] = *(const bf16x8*)&Q[(size_t)rowP * 64 + ks * 32 + g * 8];
  }

  // staging: chunk c = (i*2+wave)*64+lane; row=c>>3, src col-chunk = (c&7)^(row&7)
  int srow[4], scl[4];
#pragma unroll
  for (int i = 0; i < 4; ++i) {
    int c = (i * 2 + wave) * 64 + lane;
    srow[i] = c >> 3;
    scl[i] = (c & 7) ^ (srow[i] & 7);
  }
  auto stage = [&](int kt, int b) {
#pragma unroll
    for (int i = 0; i < 4; ++i) {
      GLOAD_LDS16(&Kh[(size_t)(kt * 64 + srow[i]) * 64 + scl[i] * 8], &Kbuf[b][(i * 2 + wave) * 512]);
      GLOAD_LDS16(&VT[(size_t)srow[i] * 2048 + kt * 64 + scl[i] * 8], &Vbuf[b][(i * 2 + wave) * 512]);
    }
  };

  f32x4 oa[4], op[4];
#pragma unroll
  for (int j = 0; j < 4; ++j) { oa[j] = (f32x4){0.f,0.f,0.f,0.f}; op[j] = (f32x4){0.f,0.f,0.f,0.f}; }
  float ma = -INFINITY, la = 0.f, mp = -INFINITY, lp = 0.f;

  auto process = [&](f32x4 (&st)[4], float& m, float& l, f32x4 (&o)[4],
                     bool domask, int rowq, int kt, const bf16x8 (&vf)[2][4]) {
    if (domask) {
#pragma unroll
      for (int j = 0; j < 4; ++j)
#pragma unroll
        for (int e = 0; e < 4; ++e)
          if (kt * 64 + j * 16 + 4 * g + e > rowq) st[j][e] = -INFINITY;
    }
    float mt = -INFINITY;
#pragma unroll
    for (int j = 0; j < 4; ++j)
#pragma unroll
      for (int e = 0; e < 4; ++e) mt = fmaxf(mt, st[j][e]);
    mt = fmaxf(mt, __shfl_xor(mt, 16, 64));
    mt = fmaxf(mt, __shfl_xor(mt, 32, 64));
    // defer-max: rescale only if some row's max grew past m+8 (rare: stable scores)
    if (!__all(mt - m <= 8.f)) {
      float mn = fmaxf(m, mt);
      float alpha = fexp2(m - mn);   // exp2(-inf)=0 on first tile
      m = mn;
      l *= alpha;
#pragma unroll
      for (int dj = 0; dj < 4; ++dj)
#pragma unroll
        for (int e = 0; e < 4; ++e) o[dj][e] *= alpha;
    }
    float ls = 0.f;
#pragma unroll
    for (int j = 0; j < 4; ++j)
#pragma unroll
      for (int e = 0; e < 4; ++e) {
        float pv = fexp2(st[j][e] - m);   // bounded by 2^8
        st[j][e] = pv;
        ls += pv;
      }
    ls += __shfl_xor(ls, 16, 64);
    ls += __shfl_xor(ls, 32, 64);
    l += ls;
#pragma unroll
    for (int j = 0; j < 4; ++j) {
      bf16x4 pk;
#pragma unroll
      for (int e = 0; e < 4; ++e) pk[e] = (__bf16)st[j][e];
      *(bf16x4*)&Plds[wave][r16][j * 16 + 4 * g] = pk;
    }
#pragma unroll
    for (int ks = 0; ks < 2; ++ks) {
      bf16x8 pf = *(const bf16x8*)&Plds[wave][r16][ks * 32 + g * 8];
#pragma unroll
      for (int dj = 0; dj < 4; ++dj)
        o[dj] = __builtin_amdgcn_mfma_f32_16x16x32_bf16(vf[ks][dj], pf, o[dj], 0, 0, 0);
    }
  };

  stage(0, 0);
  for (int kt = 0; kt < Kp; ++kt) {
    const int cur = kt & 1;
    __syncthreads();                       // drains stage(cur); guards reuse
    if (kt + 1 < Kp) stage(kt + 1, cur ^ 1);
    const bool dualA = (kt < Ka);
    f32x4 stp[4], sta[4];
#pragma unroll
    for (int j = 0; j < 4; ++j) { stp[j] = (f32x4){0.f,0.f,0.f,0.f}; sta[j] = (f32x4){0.f,0.f,0.f,0.f}; }
    __builtin_amdgcn_s_setprio(1);
#pragma unroll
    for (int ks = 0; ks < 2; ++ks)
#pragma unroll
      for (int j = 0; j < 4; ++j) {
        int row = j * 16 + r16;
        int cp = (ks * 4 + g) ^ (row & 7);
        bf16x8 kf = *(const bf16x8*)&Kbuf[cur][(row * 8 + cp) * 8];
        stp[j] = __builtin_amdgcn_mfma_f32_16x16x32_bf16(kf, qfp[ks], stp[j], 0, 0, 0);
        if (dualA) sta[j] = __builtin_amdgcn_mfma_f32_16x16x32_bf16(kf, qfa[ks], sta[j], 0, 0, 0);
      }
    __builtin_amdgcn_s_setprio(0);
    bf16x8 vf[2][4];
#pragma unroll
    for (int ks = 0; ks < 2; ++ks)
#pragma unroll
      for (int dj = 0; dj < 4; ++dj) {
        int row = dj * 16 + r16;
        int cp = (ks * 4 + g) ^ (row & 7);
        vf[ks][dj] = *(const bf16x8*)&Vbuf[cur][(row * 8 + cp) * 8];
      }
    process(stp, mp, lp, op, kt == Kp - 1, rowP, kt, vf);
    if (dualA) process(sta, ma, la, oa, kt == Ka - 1, rowA, kt, vf);
  }

  float invp = 1.0f / lp, inva = 1.0f / la;
#pragma unroll
  for (int dj = 0; dj < 4; ++dj) {
    bf16x4 ovp, ova;
#pragma unroll
    for (int e = 0; e < 4; ++e) { ovp[e] = (__bf16)(op[dj][e] * invp); ova[e] = (__bf16)(oa[dj][e] * inva); }
    *(bf16x4*)&yatt[((size_t)(bI * 2048 + rowP)) * 768 + h * 64 + dj * 16 + 4 * g] = ovp;
    *(bf16x4*)&yatt[((size_t)(bI * 2048 + rowA)) * 768 + h * 64 + dj * 16 + 4 * g] = ova;
  }
}

extern "C" void kernel_launch(void* const* d_in, const int* in_sizes, int n_in,
                              void* d_out, int out_size, void* d_ws, size_t ws_size,
                              hipStream_t stream) {
  (void)in_sizes; (void)n_in; (void)out_size; (void)ws_size;
  const float* x     = (const float*)d_in[0];
  const float* w_qkv = (const float*)d_in[1];
  const float* b_qkv = (const float*)d_in[2];
  const float* w_out = (const float*)d_in[3];
  const float* b_out = (const float*)d_in[4];
  float* out = (float*)d_out;

  char* ws = (char*)d_ws;
  __bf16* xb    = (__bf16*)(ws);              // [4096][768]
  __bf16* wqkvT = (__bf16*)(ws + 6291456);    // [2304][768]
  __bf16* woT   = (__bf16*)(ws + 9830400);    // [768][768]
  __bf16* qb    = (__bf16*)(ws + 11010048);   // [B,H,T,64]  (pre-scaled by 0.125*log2e)
  __bf16* kb    = (__bf16*)(ws + 17301504);   // [B,H,T,64]
  __bf16* vtb   = (__bf16*)(ws + 23592960);   // [B,H,64,T]  (V transposed)
  __bf16* yatt  = (__bf16*)(ws + 29884416);   // [4096][768]

  cvt_bf16_kernel<<<3072, 256, 0, stream>>>(x, xb, 786432);
  cvtT_bf16_kernel<<<dim3(72, 24), 256, 0, stream>>>(w_qkv, wqkvT, 768, 2304);
  cvtT_bf16_kernel<<<dim3(24, 24), 256, 0, stream>>>(w_out, woT, 768, 768);
  gemm_tn_kernel<0><<<dim3(18, 32), 256, 0, stream>>>(xb, wqkvT, b_qkv, nullptr,
                                                      qb, kb, vtb, 4096, 2304, 768);
  attn_kernel<<<768, 128, 0, stream>>>(qb, kb, vtb, yatt);
  gemm_tn_kernel<1><<<dim3(6, 32), 256, 0, stream>>>(yatt, woT, b_out, out,
                                                     nullptr, nullptr, nullptr, 4096, 768, 768);
}

// Round 7
// 132.574 us; speedup vs baseline: 2.1013x; 1.0164x over previous
//
#include <hip/hip_runtime.h>
#include <math.h>

// B=2, T=2048, D=768, H=12, HD=64
typedef __attribute__((ext_vector_type(8))) __bf16 bf16x8;
typedef __attribute__((ext_vector_type(4))) __bf16 bf16x4;
typedef __attribute__((ext_vector_type(4))) float f32x4;

#define GLOAD_LDS16(gsrc, ldst) \
  __builtin_amdgcn_global_load_lds((__attribute__((address_space(1))) const void*)(gsrc), \
                                   (__attribute__((address_space(3))) void*)(ldst), 16, 0, 0)

__device__ __forceinline__ float fexp2(float x) {
#if __has_builtin(__builtin_amdgcn_exp2f)
  return __builtin_amdgcn_exp2f(x);
#else
  return exp2f(x);
#endif
}

__global__ void cvt_bf16_kernel(const float* __restrict__ in, __bf16* __restrict__ out, int n4) {
  int i = blockIdx.x * 256 + threadIdx.x;
  if (i < n4) {
    float4 f = ((const float4*)in)[i];
    bf16x4 o;
    o[0] = (__bf16)f.x; o[1] = (__bf16)f.y; o[2] = (__bf16)f.z; o[3] = (__bf16)f.w;
    ((bf16x4*)out)[i] = o;
  }
}

// Tiled transpose-convert: out[C][R] = (bf16) in[R][C]. 32x32 tiles via LDS.
__global__ __launch_bounds__(256)
void cvtT_bf16_kernel(const float* __restrict__ in, __bf16* __restrict__ out, int R, int C) {
  __shared__ float t[32][33];
  int c0 = blockIdx.x * 32, r0 = blockIdx.y * 32;
  int tc = threadIdx.x & 31, tr = threadIdx.x >> 5;
#pragma unroll
  for (int i = 0; i < 4; ++i)
    t[tr + 8 * i][tc] = in[(size_t)(r0 + tr + 8 * i) * C + c0 + tc];
  __syncthreads();
#pragma unroll
  for (int i = 0; i < 4; ++i)
    out[(size_t)(c0 + tr + 8 * i) * R + r0 + tc] = (__bf16)t[tc][tr + 8 * i];
}

// TN GEMM: C[M][N] = A[M][K] * B[N][K]^T (+bias). 128xWN tile, BK=32, 4 waves.
// T3+T4 pipeline: 3 LDS buffers, prefetch distance 2, raw s_barrier with COUNTED
// vmcnt (never drains the prefetch queue except at the tail):
//   per iter { vmcnt(LPT); s_barrier; stage(t+2); ds_read+MFMA(cur) }
// Grid is 1-D, XCD-clustered: xcd = id&7 owns ppx contiguous 128-row A-panels ->
// per-XCD L2 working set ~= A panel chunk + B (L2-resident -> ~250cy load latency).
template<int EPI, int WN>
__global__ __launch_bounds__(256)
void gemm_tn_kernel(const __bf16* __restrict__ A, const __bf16* __restrict__ Bm,
                    const float* __restrict__ bias, float* __restrict__ outF,
                    __bf16* __restrict__ qo, __bf16* __restrict__ ko, __bf16* __restrict__ vo,
                    int M, int N, int K, int NBX) {
  constexpr int NSEG = 8 + WN / 16;   // 16B-chunk segments per K-step: 8 A + WN/16 B
  constexpr int LPT  = NSEG / 4;      // global_load_lds per thread per stage
  constexpr int NJ   = WN / 32;       // b-frags per wave
  const int lane = threadIdx.x & 63;
  const int wave = threadIdx.x >> 6;
  const int r16 = lane & 15, g = lane >> 4;
  // XCD clustering (bijective: gridDim.x % 8 == 0)
  const int id = blockIdx.x;
  const int xcd = id & 7, slot = id >> 3;
  const int ppx = (int)(gridDim.x >> 3) / NBX;  // A-panels per XCD
  const int by = xcd * ppx + slot / NBX;
  const int bx = slot - (slot / NBX) * NBX;
  const int mBase = by * 128, nBase = bx * WN;
  __shared__ __align__(16) __bf16 lds[3][NSEG * 512];

  f32x4 acc[4][NJ];
#pragma unroll
  for (int i = 0; i < 4; ++i)
#pragma unroll
    for (int j = 0; j < NJ; ++j) acc[i][j] = (f32x4){0.f, 0.f, 0.f, 0.f};

  const int mw = (wave >> 1) * 4;
  const int nw = (wave & 1) * NJ;

  auto stage = [&](int ke, int b) {
#pragma unroll
    for (int i = 0; i < LPT; ++i) {
      int seg = wave * LPT + i;
      int isB = seg >= 8;
      int t8 = isB ? seg - 8 : seg;
      int row = (isB ? nBase : mBase) + t8 * 16 + r16;
      const __bf16* src = (isB ? Bm : A) + (size_t)row * K + ke + g * 8;
      GLOAD_LDS16(src, &lds[b][seg * 512]);
    }
  };

  const int nt = K >> 5;
  stage(0, 0);
  stage(32, 1);
  int cur = 0;
  for (int t = 0; t < nt; ++t) {
    // wait own loads for tile t (outstanding after them = stage(t+1) = LPT), raw barrier
    if (t + 1 < nt) asm volatile("s_waitcnt vmcnt(%0)" :: "i"(LPT) : "memory");
    else            asm volatile("s_waitcnt vmcnt(0)" ::: "memory");
    __builtin_amdgcn_sched_barrier(0);
    __builtin_amdgcn_s_barrier();
    __builtin_amdgcn_sched_barrier(0);
    int nxt = cur + 2; if (nxt >= 3) nxt -= 3;
    if (t + 2 < nt) stage((t + 2) << 5, nxt);   // overwrites buf freed by this barrier
    const __bf16* L = lds[cur];
    bf16x8 af[4], bfr[NJ];
#pragma unroll
    for (int i = 0; i < 4; ++i) af[i] = *(const bf16x8*)&L[((mw + i) * 64 + lane) * 8];
#pragma unroll
    for (int j = 0; j < NJ; ++j) bfr[j] = *(const bf16x8*)&L[((8 + nw + j) * 64 + lane) * 8];
    __builtin_amdgcn_s_setprio(1);
#pragma unroll
    for (int i = 0; i < 4; ++i)
#pragma unroll
      for (int j = 0; j < NJ; ++j)
        acc[i][j] = __builtin_amdgcn_mfma_f32_16x16x32_bf16(af[i], bfr[j], acc[i][j], 0, 0, 0);
    __builtin_amdgcn_s_setprio(0);
    if (++cur == 3) cur = 0;
  }

#pragma unroll
  for (int i = 0; i < 4; ++i) {
#pragma unroll
    for (int j = 0; j < NJ; ++j) {
      int c = nBase + (nw + j) * 16 + r16;
      float bb = bias[c];
#pragma unroll
      for (int e = 0; e < 4; ++e) {
        int r = mBase + (mw + i) * 16 + g * 4 + e;
        float val = acc[i][j][e] + bb;
        if (EPI == 0) {
          int which = c / 768;             // 0:q 1:k 2:v
          int cc = c - which * 768;
          int hh = cc >> 6, dd = cc & 63;
          int bI = r >> 11, tt = r & 2047;
          if (which == 0) {
            // fold 1/sqrt(64) * log2(e) into q (softmax runs in exp2 space)
            qo[(((size_t)(bI * 12 + hh)) * 2048 + tt) * 64 + dd] = (__bf16)(val * 0.180336880f);
          } else if (which == 1) {
            ko[(((size_t)(bI * 12 + hh)) * 2048 + tt) * 64 + dd] = (__bf16)val;
          } else {
            vo[(((size_t)(bI * 12 + hh)) * 64 + dd) * 2048 + tt] = (__bf16)val;  // V^T [B,H,64,T]
          }
        } else {
          outF[(size_t)r * N + c] = val;
        }
      }
    }
  }
}

// Flash attention, causal, swapped-QK^T, O^T accumulation, causal-paired tiles.
// (unchanged from R6)
__global__ __launch_bounds__(128, 2)
void attn_kernel(const __bf16* __restrict__ qg, const __bf16* __restrict__ kg,
                 const __bf16* __restrict__ vtg, __bf16* __restrict__ yatt) {
  const int id = blockIdx.x;
  const int chunk = id & 7, within = id >> 3;   // XCD chunk = 3 heads (L2-resident K/V)
  const int bh = chunk * 3 + (within >> 5);
  const int a = within & 31, p = 63 - a;        // paired 32-row q-tiles
  const int Ka = (a >> 1) + 1, Kp = (p >> 1) + 1;
  const int lane = threadIdx.x & 63, wave = threadIdx.x >> 6;  // wave in {0,1}
  const int r16 = lane & 15, g = lane >> 4;
  const int bI = bh / 12, h = bh - bI * 12;
  const size_t headoff = (size_t)bh * 2048 * 64;
  const __bf16* Q = qg + headoff;
  const __bf16* Kh = kg + headoff;
  const __bf16* VT = vtg + headoff;             // [64][2048]

  __shared__ __align__(16) __bf16 Kbuf[2][4096];
  __shared__ __align__(16) __bf16 Vbuf[2][4096];
  __shared__ __align__(16) __bf16 Plds[2][16][72];

  const int rowA = a * 32 + wave * 16 + r16;
  const int rowP = p * 32 + wave * 16 + r16;
  bf16x8 qfa[2], qfp[2];
#pragma unroll
  for (int ks = 0; ks < 2; ++ks) {
    qfa[ks] = *(const bf16x8*)&Q[(size_t)rowA * 64 + ks * 32 + g * 8];
    qfp[ks] = *(const bf16x8*)&Q[(size_t)rowP * 64 + ks * 32 + g * 8];
  }

  int srow[4], scl[4];
#pragma unroll
  for (int i = 0; i < 4; ++i) {
    int c = (i * 2 + wave) * 64 + lane;
    srow[i] = c >> 3;
    scl[i] = (c & 7) ^ (srow[i] & 7);
  }
  auto stage = [&](int kt, int b) {
#pragma unroll
    for (int i = 0; i < 4; ++i) {
      GLOAD_LDS16(&Kh[(size_t)(kt * 64 + srow[i]) * 64 + scl[i] * 8], &Kbuf[b][(i * 2 + wave) * 512]);
      GLOAD_LDS16(&VT[(size_t)srow[i] * 2048 + kt * 64 + scl[i] * 8], &Vbuf[b][(i * 2 + wave) * 512]);
    }
  };

  f32x4 oa[4], op[4];
#pragma unroll
  for (int j = 0; j < 4; ++j) { oa[j] = (f32x4){0.f,0.f,0.f,0.f}; op[j] = (f32x4){0.f,0.f,0.f,0.f}; }
  float ma = -INFINITY, la = 0.f, mp = -INFINITY, lp = 0.f;

  auto process = [&](f32x4 (&st)[4], float& m, float& l, f32x4 (&o)[4],
                     bool domask, int rowq, int kt, const bf16x8 (&vf)[2][4]) {
    if (domask) {
#pragma unroll
      for (int j = 0; j < 4; ++j)
#pragma unroll
        for (int e = 0; e < 4; ++e)
          if (kt * 64 + j * 16 + 4 * g + e > rowq) st[j][e] = -INFINITY;
    }
    float mt = -INFINITY;
#pragma unroll
    for (int j = 0; j < 4; ++j)
#pragma unroll
      for (int e = 0; e < 4; ++e) mt = fmaxf(mt, st[j][e]);
    mt = fmaxf(mt, __shfl_xor(mt, 16, 64));
    mt = fmaxf(mt, __shfl_xor(mt, 32, 64));
    if (!__all(mt - m <= 8.f)) {
      float mn = fmaxf(m, mt);
      float alpha = fexp2(m - mn);
      m = mn;
      l *= alpha;
#pragma unroll
      for (int dj = 0; dj < 4; ++dj)
#pragma unroll
        for (int e = 0; e < 4; ++e) o[dj][e] *= alpha;
    }
    float ls = 0.f;
#pragma unroll
    for (int j = 0; j < 4; ++j)
#pragma unroll
      for (int e = 0; e < 4; ++e) {
        float pv = fexp2(st[j][e] - m);
        st[j][e] = pv;
        ls += pv;
      }
    ls += __shfl_xor(ls, 16, 64);
    ls += __shfl_xor(ls, 32, 64);
    l += ls;
#pragma unroll
    for (int j = 0; j < 4; ++j) {
      bf16x4 pk;
#pragma unroll
      for (int e = 0; e < 4; ++e) pk[e] = (__bf16)st[j][e];
      *(bf16x4*)&Plds[wave][r16][j * 16 + 4 * g] = pk;
    }
#pragma unroll
    for (int ks = 0; ks < 2; ++ks) {
      bf16x8 pf = *(const bf16x8*)&Plds[wave][r16][ks * 32 + g * 8];
#pragma unroll
      for (int dj = 0; dj < 4; ++dj)
        o[dj] = __builtin_amdgcn_mfma_f32_16x16x32_bf16(vf[ks][dj], pf, o[dj], 0, 0, 0);
    }
  };

  stage(0, 0);
  for (int kt = 0; kt < Kp; ++kt) {
    const int cur = kt & 1;
    __syncthreads();
    if (kt + 1 < Kp) stage(kt + 1, cur ^ 1);
    const bool dualA = (kt < Ka);
    f32x4 stp[4], sta[4];
#pragma unroll
    for (int j = 0; j < 4; ++j) { stp[j] = (f32x4){0.f,0.f,0.f,0.f}; sta[j] = (f32x4){0.f,0.f,0.f,0.f}; }
    __builtin_amdgcn_s_setprio(1);
#pragma unroll
    for (int ks = 0; ks < 2; ++ks)
#pragma unroll
      for (int j = 0; j < 4; ++j) {
        int row = j * 16 + r16;
        int cp = (ks * 4 + g) ^ (row & 7);
        bf16x8 kf = *(const bf16x8*)&Kbuf[cur][(row * 8 + cp) * 8];
        stp[j] = __builtin_amdgcn_mfma_f32_16x16x32_bf16(kf, qfp[ks], stp[j], 0, 0, 0);
        if (dualA) sta[j] = __builtin_amdgcn_mfma_f32_16x16x32_bf16(kf, qfa[ks], sta[j], 0, 0, 0);
      }
    __builtin_amdgcn_s_setprio(0);
    bf16x8 vf[2][4];
#pragma unroll
    for (int ks = 0; ks < 2; ++ks)
#pragma unroll
      for (int dj = 0; dj < 4; ++dj) {
        int row = dj * 16 + r16;
        int cp = (ks * 4 + g) ^ (row & 7);
        vf[ks][dj] = *(const bf16x8*)&Vbuf[cur][(row * 8 + cp) * 8];
      }
    process(stp, mp, lp, op, kt == Kp - 1, rowP, kt, vf);
    if (dualA) process(sta, ma, la, oa, kt == Ka - 1, rowA, kt, vf);
  }

  float invp = 1.0f / lp, inva = 1.0f / la;
#pragma unroll
  for (int dj = 0; dj < 4; ++dj) {
    bf16x4 ovp, ova;
#pragma unroll
    for (int e = 0; e < 4; ++e) { ovp[e] = (__bf16)(op[dj][e] * invp); ova[e] = (__bf16)(oa[dj][e] * inva); }
    *(bf16x4*)&yatt[((size_t)(bI * 2048 + rowP)) * 768 + h * 64 + dj * 16 + 4 * g] = ovp;
    *(bf16x4*)&yatt[((size_t)(bI * 2048 + rowA)) * 768 + h * 64 + dj * 16 + 4 * g] = ova;
  }
}

extern "C" void kernel_launch(void* const* d_in, const int* in_sizes, int n_in,
                              void* d_out, int out_size, void* d_ws, size_t ws_size,
                              hipStream_t stream) {
  (void)in_sizes; (void)n_in; (void)out_size; (void)ws_size;
  const float* x     = (const float*)d_in[0];
  const float* w_qkv = (const float*)d_in[1];
  const float* b_qkv = (const float*)d_in[2];
  const float* w_out = (const float*)d_in[3];
  const float* b_out = (const float*)d_in[4];
  float* out = (float*)d_out;

  char* ws = (char*)d_ws;
  __bf16* xb    = (__bf16*)(ws);              // [4096][768]
  __bf16* wqkvT = (__bf16*)(ws + 6291456);    // [2304][768]
  __bf16* woT   = (__bf16*)(ws + 9830400);    // [768][768]
  __bf16* qb    = (__bf16*)(ws + 11010048);   // [B,H,T,64]  (pre-scaled by 0.125*log2e)
  __bf16* kb    = (__bf16*)(ws + 17301504);   // [B,H,T,64]
  __bf16* vtb   = (__bf16*)(ws + 23592960);   // [B,H,64,T]  (V transposed)
  __bf16* yatt  = (__bf16*)(ws + 29884416);   // [4096][768]

  cvt_bf16_kernel<<<3072, 256, 0, stream>>>(x, xb, 786432);
  cvtT_bf16_kernel<<<dim3(72, 24), 256, 0, stream>>>(w_qkv, wqkvT, 768, 2304);
  cvtT_bf16_kernel<<<dim3(24, 24), 256, 0, stream>>>(w_out, woT, 768, 768);
  gemm_tn_kernel<0, 128><<<576, 256, 0, stream>>>(xb, wqkvT, b_qkv, nullptr,
                                                  qb, kb, vtb, 4096, 2304, 768, 18);
  attn_kernel<<<768, 128, 0, stream>>>(qb, kb, vtb, yatt);
  gemm_tn_kernel<1, 64><<<384, 256, 0, stream>>>(yatt, woT, b_out, out,
                                                 nullptr, nullptr, nullptr, 4096, 768, 768, 12);
}